// Round 1
// 18916.182 us; speedup vs baseline: 2.3181x; 2.3181x over previous
//
#include <hip/hip_runtime.h>
#include <hip/hip_bf16.h>

typedef __bf16 bf16_t;
typedef __bf16 bf16x8 __attribute__((ext_vector_type(8)));
typedef float  f32x4  __attribute__((ext_vector_type(4)));
typedef unsigned long long u64;

#define S_LEN 1024
#define NBLK  64   // persistent blocks; each owns 16 r + 16 z + 16 n feature rows
#define FLAG_STRIDE 64  // dwords: one flag per 256B line to avoid LLC line contention

__device__ inline f32x4 mfma16(bf16x8 a, bf16x8 b, f32x4 c) {
  return __builtin_amdgcn_mfma_f32_16x16x32_bf16(a, b, c, 0, 0, 0);
}
__device__ inline float fsigmoid(float x) {
  x = fmaxf(-30.f, fminf(30.f, x));
  return 1.f / (1.f + __expf(-x));
}
__device__ inline float ftanh(float x) {
  x = fmaxf(-15.f, fminf(15.f, x));
  float e = __expf(2.f * x);
  return (e - 1.f) / (e + 1.f);
}

// Agent-scope relaxed store = global_store_short sc1: writes THROUGH the
// per-XCD (non-coherent) L2 to the device coherence point. This is what lets
// the barrier drop buffer_wbl2 entirely: nothing cross-block ever sits dirty in L2.
__device__ inline void st_coh_bf16(bf16_t* p, float v) {
  bf16_t b = (bf16_t)v;
  __hip_atomic_store((unsigned short*)p, __builtin_bit_cast(unsigned short, b),
                     __ATOMIC_RELAXED, __HIP_MEMORY_SCOPE_AGENT);
}

// ---------------- cast input fp32 -> bf16 ----------------
__global__ void k_cast_x(const float* __restrict__ x, bf16_t* __restrict__ xb, int n8) {
  int i = blockIdx.x * blockDim.x + threadIdx.x;
  if (i >= n8) return;
  const float4* p = (const float4*)(x + (size_t)i * 8);
  float4 a = p[0], b = p[1];
  bf16x8 o;
  o[0]=(bf16_t)a.x; o[1]=(bf16_t)a.y; o[2]=(bf16_t)a.z; o[3]=(bf16_t)a.w;
  o[4]=(bf16_t)b.x; o[5]=(bf16_t)b.y; o[6]=(bf16_t)b.z; o[7]=(bf16_t)b.w;
  *(bf16x8*)(xb + (size_t)i * 8) = o;
}

// ---------------- pack weights (r,z,n concatenated rows), fold biases ----------------
__global__ void k_prep_w(const float* __restrict__ wihr, const float* __restrict__ whhr,
                         const float* __restrict__ wihz, const float* __restrict__ whhz,
                         const float* __restrict__ wihn, const float* __restrict__ whhn,
                         const float* __restrict__ bihr, const float* __restrict__ bhhr,
                         const float* __restrict__ bihz, const float* __restrict__ bhhz,
                         const float* __restrict__ bihn, const float* __restrict__ bhhn,
                         bf16_t* __restrict__ wih, bf16_t* __restrict__ whh,
                         float* __restrict__ bias) {
  int i = blockIdx.x * blockDim.x + threadIdx.x;
  const int M = 1024 * 1024;
  if (i < M) {
    wih[i]       = (bf16_t)wihr[i];
    wih[M + i]   = (bf16_t)wihz[i];
    wih[2*M + i] = (bf16_t)wihn[i];
    whh[i]       = (bf16_t)whhr[i];
    whh[M + i]   = (bf16_t)whhz[i];
    whh[2*M + i] = (bf16_t)whhn[i];
  }
  if (i < 1024) {
    bias[i]        = bihr[i] + bhhr[i];
    bias[1024 + i] = bihz[i] + bhhz[i];
    bias[2048 + i] = bihn[i] + bhhn[i];
  }
}

// ---------------- batched input-projection GEMM ----------------
// C[m][f] = sum_k Xb[m][k] * W[f][k] + bias[f];  M=65536, N=3072, K=1024
// f < 2048 -> bf16 xrz[m][f];  f >= 2048 -> fp32 xn staged into d_out[m][f-2048]
__global__ __launch_bounds__(256) void k_gemm(
    const bf16_t* __restrict__ A, const bf16_t* __restrict__ B,
    const float* __restrict__ bias,
    bf16_t* __restrict__ xrz, float* __restrict__ xn)
{
  __shared__ __align__(16) bf16_t As[128 * 32];
  __shared__ __align__(16) bf16_t Bs[128 * 32];
  const int tid  = threadIdx.x;
  const int lane = tid & 63;
  const int wid  = tid >> 6;
  const int wm   = wid & 1, wn = wid >> 1;
  const int quad = lane >> 4, l15 = lane & 15;
  const int m0 = blockIdx.x * 128;
  const int f0 = blockIdx.y * 128;

  const int r0 = tid >> 2,         o0 = (tid & 3) * 8;
  const int r1 = (tid + 256) >> 2, o1 = ((tid + 256) & 3) * 8;

  const bf16_t* Ag = A + (size_t)m0 * 1024;
  const bf16_t* Bg = B + (size_t)f0 * 1024;

  f32x4 acc[4][4] = {};

  bf16x8 pa0 = *(const bf16x8*)(Ag + r0 * 1024 + o0);
  bf16x8 pa1 = *(const bf16x8*)(Ag + r1 * 1024 + o1);
  bf16x8 pb0 = *(const bf16x8*)(Bg + r0 * 1024 + o0);
  bf16x8 pb1 = *(const bf16x8*)(Bg + r1 * 1024 + o1);

  for (int k0 = 0; k0 < 1024; k0 += 32) {
    __syncthreads();
    *(bf16x8*)&As[r0 * 32 + o0] = pa0;
    *(bf16x8*)&As[r1 * 32 + o1] = pa1;
    *(bf16x8*)&Bs[r0 * 32 + o0] = pb0;
    *(bf16x8*)&Bs[r1 * 32 + o1] = pb1;
    __syncthreads();
    if (k0 + 32 < 1024) {               // prefetch next K-slab under the MFMAs
      const bf16_t* Ag2 = Ag + k0 + 32;
      const bf16_t* Bg2 = Bg + k0 + 32;
      pa0 = *(const bf16x8*)(Ag2 + r0 * 1024 + o0);
      pa1 = *(const bf16x8*)(Ag2 + r1 * 1024 + o1);
      pb0 = *(const bf16x8*)(Bg2 + r0 * 1024 + o0);
      pb1 = *(const bf16x8*)(Bg2 + r1 * 1024 + o1);
    }
    bf16x8 af[4], bfr[4];
#pragma unroll
    for (int t = 0; t < 4; t++) {
      af[t]  = *(const bf16x8*)&As[(wm * 64 + t * 16 + l15) * 32 + quad * 8];
      bfr[t] = *(const bf16x8*)&Bs[(wn * 64 + t * 16 + l15) * 32 + quad * 8];
    }
#pragma unroll
    for (int mt = 0; mt < 4; mt++)
#pragma unroll
      for (int nt = 0; nt < 4; nt++)
        acc[mt][nt] = mfma16(af[mt], bfr[nt], acc[mt][nt]);
  }

  float bcol[4];
#pragma unroll
  for (int nt = 0; nt < 4; nt++) bcol[nt] = bias[f0 + wn * 64 + nt * 16 + l15];

  const bool is_n = (blockIdx.y >= 16);
#pragma unroll
  for (int mt = 0; mt < 4; mt++) {
#pragma unroll
    for (int nt = 0; nt < 4; nt++) {
#pragma unroll
      for (int j = 0; j < 4; j++) {
        int m = m0 + wm * 64 + mt * 16 + quad * 4 + j;   // C row = quad*4+reg (m89)
        int f = f0 + wn * 64 + nt * 16 + l15;            // C col = lane&15
        float v = acc[mt][nt][j] + bcol[nt];
        if (!is_n) xrz[(size_t)m * 2048 + f] = (bf16_t)v;
        else       xn[(size_t)m * 1024 + (f - 2048)] = v;
      }
    }
  }
}

// ---------------- flag init (ws is 0xAA-poisoned; barrier needs zeros) ----------------
__global__ void k_zero_flags(unsigned* f) {
  for (int i = threadIdx.x; i < NBLK * FLAG_STRIDE; i += 256) f[i] = 0;
}

// Monotone-counter grid barrier, fence-light version.
// Release side: all cross-block data was stored with sc1 (write-through), so a
// plain vmcnt(0) drain makes it globally visible — NO buffer_wbl2 (the full-L2
// dirty-writeback scan that two __threadfence()s per barrier used to pay).
// Acquire side: one agent acquire fence (buffer_inv only) so the following
// PLAIN GEMV loads refetch fresh lines from the LLC (then L2-shared by the
// 8 blocks co-resident per XCD).
__device__ inline void gridbar(unsigned* flags, int bid, unsigned p) {
  asm volatile("s_waitcnt vmcnt(0)" ::: "memory");   // per-wave store drain
  __syncthreads();
  if (threadIdx.x == 0)
    __hip_atomic_store(&flags[bid * FLAG_STRIDE], p, __ATOMIC_RELAXED,
                       __HIP_MEMORY_SCOPE_AGENT);
  if (threadIdx.x < NBLK) {
    while (__hip_atomic_load(&flags[threadIdx.x * FLAG_STRIDE], __ATOMIC_RELAXED,
                             __HIP_MEMORY_SCOPE_AGENT) < p)
      __builtin_amdgcn_s_sleep(1);
  }
  __syncthreads();
  __builtin_amdgcn_fence(__ATOMIC_ACQUIRE, "agent"); // buffer_inv, no writeback
}

// ---------------- persistent recurrent kernel ----------------
// Block bid owns feature columns [bid*16, bid*16+16) of r, z, n. W_hh rows LDS-resident.
// Wave w handles batches [16w, 16w+16). h lives in 4 regs/thread (same thread
// produces and consumes h[b][fg] every step); hb is the bf16 exchange copy.
__global__ __launch_bounds__(256) void k_gru(
    const bf16_t* __restrict__ xrz,  // [65536][2048] bf16 (bias folded)
    const bf16_t* __restrict__ whh,  // [3072][1024] bf16 (r,z,n rows)
    float* __restrict__ out,         // [S*64*1024] holds xn, overwritten with h; +[64*1024] h_n
    bf16_t* __restrict__ hb,
    bf16_t* __restrict__ rh, unsigned* __restrict__ flags)
{
  __shared__ __align__(16) bf16_t wl[48 * 1032];   // 48 rows, +8 bf16 pad (99 KB)
  const int tid  = threadIdx.x;
  const int bid  = blockIdx.x;
  const int lane = tid & 63;
  const int wid  = tid >> 6;
  const int quad = lane >> 4, l15 = lane & 15;

  // stage this block's 48 W_hh rows into LDS
  for (int i = tid; i < 48 * 128; i += 256) {
    int row = i >> 7;            // 0..47 (0-15 r, 16-31 z, 32-47 n)
    int c   = (i & 127) * 8;
    int gr  = (row >> 4) * 1024 + bid * 16 + (row & 15);
    *(bf16x8*)&wl[row * 1032 + c] = *(const bf16x8*)&whh[(size_t)gr * 1024 + c];
  }
  // zero h exchange copy via coherent stores (plain stores could sit dirty in
  // the local XCD L2 and be invisible to remote readers — no wbl2 anywhere now)
  for (int i = tid; i < 64 * 4; i += 256) {
    int b = i >> 2, c = i & 3;
    __hip_atomic_store((u64*)(hb + (size_t)b * 1024 + bid * 16) + c, 0ull,
                       __ATOMIC_RELAXED, __HIP_MEMORY_SCOPE_AGENT);
  }
  gridbar(flags, bid, 1);

  const int abase = (wid * 16 + l15) * 1024 + quad * 8;  // A-frag: m=lane&15 (m120)
  const int fg = bid * 16 + l15;                         // this lane's feature column
  unsigned p = 2;

  float hreg[4] = {0.f, 0.f, 0.f, 0.f};     // h[b][fg], thread-private across steps
  float xr_pf[4], xz_pf[4], xn_pf[4];       // operand prefetch regs (survive buffer_inv)
#pragma unroll
  for (int j = 0; j < 4; j++) {
    int b = wid * 16 + quad * 4 + j;
    xr_pf[j] = (float)xrz[(size_t)b * 2048 + fg];
    xz_pf[j] = (float)xrz[(size_t)b * 2048 + 1024 + fg];
  }

  for (int t = 0; t < S_LEN; t++) {
    const int mrow = t * 64;

    // ---- phase A: r,z GEMVs + rh ----
    f32x4 ar = {}, az = {};
    const bf16_t* hrow = hb + abase;
#pragma unroll 4
    for (int kk = 0; kk < 32; kk++) {
      bf16x8 a  = *(const bf16x8*)(hrow + kk * 32);
      bf16x8 br = *(const bf16x8*)&wl[l15 * 1032 + kk * 32 + quad * 8];
      bf16x8 bz = *(const bf16x8*)&wl[(16 + l15) * 1032 + kk * 32 + quad * 8];
      ar = mfma16(a, br, ar);
      az = mfma16(a, bz, az);
    }
    float zreg[4];
#pragma unroll
    for (int j = 0; j < 4; j++) {
      int b = wid * 16 + quad * 4 + j;                   // C row = quad*4+reg
      float rv = fsigmoid(xr_pf[j] + ar[j]);
      float zv = fsigmoid(xz_pf[j] + az[j]);
      zreg[j] = zv;
      st_coh_bf16(&rh[b * 1024 + fg], rv * hreg[j]);     // write-through exchange
    }
    // prefetch xn(t) into regs: completes while rh drains / barrier spins,
    // and so survives the barrier's buffer_inv
#pragma unroll
    for (int j = 0; j < 4; j++) {
      int b = wid * 16 + quad * 4 + j;
      xn_pf[j] = out[(size_t)(mrow + b) * 1024 + fg];
    }
    gridbar(flags, bid, p); p++;

    // ---- phase B: n GEMV + state update ----
    f32x4 an = {};
    const bf16_t* rrow = rh + abase;
#pragma unroll 4
    for (int kk = 0; kk < 32; kk++) {
      bf16x8 a  = *(const bf16x8*)(rrow + kk * 32);
      bf16x8 bn = *(const bf16x8*)&wl[(32 + l15) * 1032 + kk * 32 + quad * 8];
      an = mfma16(a, bn, an);
    }
#pragma unroll
    for (int j = 0; j < 4; j++) {
      int b = wid * 16 + quad * 4 + j;
      size_t oix = (size_t)(mrow + b) * 1024 + fg;
      float nv  = ftanh(xn_pf[j] + an[j]);
      float hv  = (1.f - zreg[j]) * nv + zreg[j] * hreg[j];
      hreg[j] = hv;
      out[oix] = hv;                                     // block-private: plain store
      st_coh_bf16(&hb[b * 1024 + fg], hv);               // write-through exchange
      if (t == S_LEN - 1) out[(size_t)S_LEN * 64 * 1024 + b * 1024 + fg] = hv;
    }
    if (t + 1 < S_LEN) {
      // prefetch next step's xr/xz before the barrier (hides post-inv refetch)
#pragma unroll
      for (int j = 0; j < 4; j++) {
        int b = wid * 16 + quad * 4 + j;
        xr_pf[j] = (float)xrz[(size_t)(mrow + 64 + b) * 2048 + fg];
        xz_pf[j] = (float)xrz[(size_t)(mrow + 64 + b) * 2048 + 1024 + fg];
      }
      gridbar(flags, bid, p); p++;
    }
    // last step: no trailing barrier needed; exited blocks leave flags at max,
    // monotone >= test keeps any stragglers deadlock-free
  }
}

extern "C" void kernel_launch(void* const* d_in, const int* in_sizes, int n_in,
                              void* d_out, int out_size, void* d_ws, size_t ws_size,
                              hipStream_t stream) {
  const float* x    = (const float*)d_in[0];
  const float* wihr = (const float*)d_in[1];
  const float* whhr = (const float*)d_in[2];
  const float* wihz = (const float*)d_in[3];
  const float* whhz = (const float*)d_in[4];
  const float* wihn = (const float*)d_in[5];
  const float* whhn = (const float*)d_in[6];
  const float* bihr = (const float*)d_in[7];
  const float* bhhr = (const float*)d_in[8];
  const float* bihz = (const float*)d_in[9];
  const float* bhhz = (const float*)d_in[10];
  const float* bihn = (const float*)d_in[11];
  const float* bhhn = (const float*)d_in[12];
  float* out = (float*)d_out;

  // ws layout (≈396.5 MiB, unchanged footprint; flags reuse the old hf slot)
  char* w = (char*)d_ws;
  bf16_t*  Xb    = (bf16_t*)(w);                    // 134,217,728 B
  bf16_t*  xrz   = (bf16_t*)(w + 134217728);        // 268,435,456 B
  bf16_t*  wih   = (bf16_t*)(w + 402653184);        //   6,291,456 B
  bf16_t*  whh   = (bf16_t*)(w + 408944640);        //   6,291,456 B
  float*   bias  = (float*) (w + 415236096);        //      12,288 B
  unsigned* flags = (unsigned*)(w + 415248384);     //  16,384 B (padded, old hf slot)
  bf16_t*  hb    = (bf16_t*)(w + 415510528);        //     131,072 B
  bf16_t*  rh    = (bf16_t*)(w + 415641600);        //     131,072 B

  k_cast_x<<<dim3(8388608 / 256), dim3(256), 0, stream>>>(x, Xb, 8388608);
  k_prep_w<<<dim3(1048576 / 256), dim3(256), 0, stream>>>(
      wihr, whhr, wihz, whhz, wihn, whhn,
      bihr, bhhr, bihz, bhhz, bihn, bhhn, wih, whh, bias);
  k_gemm<<<dim3(512, 24), dim3(256), 0, stream>>>(Xb, wih, bias, xrz, out);
  k_zero_flags<<<dim3(1), dim3(256), 0, stream>>>(flags);
  // 64 blocks on 256 CUs: all co-resident on dispatch (plain launch; custom barrier
  // uses monotone counters so a missed value cannot deadlock).
  k_gru<<<dim3(NBLK), dim3(256), 0, stream>>>(xrz, whh, out, hb, rh, flags);
}

// Round 3
// 13602.505 us; speedup vs baseline: 3.2237x; 1.3906x over previous
//
#include <hip/hip_runtime.h>
#include <hip/hip_bf16.h>

typedef __bf16 bf16_t;
typedef __bf16 bf16x8 __attribute__((ext_vector_type(8)));
typedef float  f32x4  __attribute__((ext_vector_type(4)));
typedef unsigned long long u64;

#define S_LEN 1024
#define NBLK  64   // persistent blocks; each owns 16 r + 16 z + 16 n feature rows
#define FLAG_STRIDE 64  // dwords: one flag per 256B line to avoid LLC line contention

__device__ inline f32x4 mfma16(bf16x8 a, bf16x8 b, f32x4 c) {
  return __builtin_amdgcn_mfma_f32_16x16x32_bf16(a, b, c, 0, 0, 0);
}
__device__ inline float fsigmoid(float x) {
  x = fmaxf(-30.f, fminf(30.f, x));
  return 1.f / (1.f + __expf(-x));
}
__device__ inline float ftanh(float x) {
  x = fmaxf(-15.f, fminf(15.f, x));
  float e = __expf(2.f * x);
  return (e - 1.f) / (e + 1.f);
}

// Write-through store (sc1): cross-block data never sits dirty in the
// non-coherent per-XCD L2; a plain vmcnt drain makes it globally visible.
__device__ inline void st_coh_bf16(bf16_t* p, float v) {
  bf16_t b = (bf16_t)v;
  __hip_atomic_store((unsigned short*)p, __builtin_bit_cast(unsigned short, b),
                     __ATOMIC_RELAXED, __HIP_MEMORY_SCOPE_AGENT);
}

// Coherence-BYPASSING 16B load (sc0 sc1): misses L1 and L2, reads the
// coherence point directly. This replaces the per-barrier buffer_inv —
// stale L1/L2 lines for hb/rh can simply never be observed.
__device__ __forceinline__ bf16x8 ld_coh(const bf16_t* p) {
  f32x4 r;
  asm volatile("global_load_dwordx4 %0, %1, off sc0 sc1" : "=v"(r) : "v"(p));
  return __builtin_bit_cast(bf16x8, r);
}

// ---------------- cast input fp32 -> bf16 ----------------
__global__ void k_cast_x(const float* __restrict__ x, bf16_t* __restrict__ xb, int n8) {
  int i = blockIdx.x * blockDim.x + threadIdx.x;
  if (i >= n8) return;
  const float4* p = (const float4*)(x + (size_t)i * 8);
  float4 a = p[0], b = p[1];
  bf16x8 o;
  o[0]=(bf16_t)a.x; o[1]=(bf16_t)a.y; o[2]=(bf16_t)a.z; o[3]=(bf16_t)a.w;
  o[4]=(bf16_t)b.x; o[5]=(bf16_t)b.y; o[6]=(bf16_t)b.z; o[7]=(bf16_t)b.w;
  *(bf16x8*)(xb + (size_t)i * 8) = o;
}

// ---------------- pack weights (r,z,n concatenated rows), fold biases ----------------
__global__ void k_prep_w(const float* __restrict__ wihr, const float* __restrict__ whhr,
                         const float* __restrict__ wihz, const float* __restrict__ whhz,
                         const float* __restrict__ wihn, const float* __restrict__ whhn,
                         const float* __restrict__ bihr, const float* __restrict__ bhhr,
                         const float* __restrict__ bihz, const float* __restrict__ bhhz,
                         const float* __restrict__ bihn, const float* __restrict__ bhhn,
                         bf16_t* __restrict__ wih, bf16_t* __restrict__ whh,
                         float* __restrict__ bias) {
  int i = blockIdx.x * blockDim.x + threadIdx.x;
  const int M = 1024 * 1024;
  if (i < M) {
    wih[i]       = (bf16_t)wihr[i];
    wih[M + i]   = (bf16_t)wihz[i];
    wih[2*M + i] = (bf16_t)wihn[i];
    whh[i]       = (bf16_t)whhr[i];
    whh[M + i]   = (bf16_t)whhz[i];
    whh[2*M + i] = (bf16_t)whhn[i];
  }
  if (i < 1024) {
    bias[i]        = bihr[i] + bhhr[i];
    bias[1024 + i] = bihz[i] + bhhz[i];
    bias[2048 + i] = bihn[i] + bhhn[i];
  }
}

// ---------------- batched input-projection GEMM ----------------
// C[m][f] = sum_k Xb[m][k] * W[f][k] + bias[f];  M=65536, N=3072, K=1024
// f < 2048 -> bf16 xrz[m][f];  f >= 2048 -> fp32 xn staged into d_out[m][f-2048]
__global__ __launch_bounds__(256) void k_gemm(
    const bf16_t* __restrict__ A, const bf16_t* __restrict__ B,
    const float* __restrict__ bias,
    bf16_t* __restrict__ xrz, float* __restrict__ xn)
{
  __shared__ __align__(16) bf16_t As[128 * 32];
  __shared__ __align__(16) bf16_t Bs[128 * 32];
  const int tid  = threadIdx.x;
  const int lane = tid & 63;
  const int wid  = tid >> 6;
  const int wm   = wid & 1, wn = wid >> 1;
  const int quad = lane >> 4, l15 = lane & 15;
  const int m0 = blockIdx.x * 128;
  const int f0 = blockIdx.y * 128;

  const int r0 = tid >> 2,         o0 = (tid & 3) * 8;
  const int r1 = (tid + 256) >> 2, o1 = ((tid + 256) & 3) * 8;

  const bf16_t* Ag = A + (size_t)m0 * 1024;
  const bf16_t* Bg = B + (size_t)f0 * 1024;

  f32x4 acc[4][4] = {};

  bf16x8 pa0 = *(const bf16x8*)(Ag + r0 * 1024 + o0);
  bf16x8 pa1 = *(const bf16x8*)(Ag + r1 * 1024 + o1);
  bf16x8 pb0 = *(const bf16x8*)(Bg + r0 * 1024 + o0);
  bf16x8 pb1 = *(const bf16x8*)(Bg + r1 * 1024 + o1);

  for (int k0 = 0; k0 < 1024; k0 += 32) {
    __syncthreads();
    *(bf16x8*)&As[r0 * 32 + o0] = pa0;
    *(bf16x8*)&As[r1 * 32 + o1] = pa1;
    *(bf16x8*)&Bs[r0 * 32 + o0] = pb0;
    *(bf16x8*)&Bs[r1 * 32 + o1] = pb1;
    __syncthreads();
    if (k0 + 32 < 1024) {               // prefetch next K-slab under the MFMAs
      const bf16_t* Ag2 = Ag + k0 + 32;
      const bf16_t* Bg2 = Bg + k0 + 32;
      pa0 = *(const bf16x8*)(Ag2 + r0 * 1024 + o0);
      pa1 = *(const bf16x8*)(Ag2 + r1 * 1024 + o1);
      pb0 = *(const bf16x8*)(Bg2 + r0 * 1024 + o0);
      pb1 = *(const bf16x8*)(Bg2 + r1 * 1024 + o1);
    }
    bf16x8 af[4], bfr[4];
#pragma unroll
    for (int t = 0; t < 4; t++) {
      af[t]  = *(const bf16x8*)&As[(wm * 64 + t * 16 + l15) * 32 + quad * 8];
      bfr[t] = *(const bf16x8*)&Bs[(wn * 64 + t * 16 + l15) * 32 + quad * 8];
    }
#pragma unroll
    for (int mt = 0; mt < 4; mt++)
#pragma unroll
      for (int nt = 0; nt < 4; nt++)
        acc[mt][nt] = mfma16(af[mt], bfr[nt], acc[mt][nt]);
  }

  float bcol[4];
#pragma unroll
  for (int nt = 0; nt < 4; nt++) bcol[nt] = bias[f0 + wn * 64 + nt * 16 + l15];

  const bool is_n = (blockIdx.y >= 16);
#pragma unroll
  for (int mt = 0; mt < 4; mt++) {
#pragma unroll
    for (int nt = 0; nt < 4; nt++) {
#pragma unroll
      for (int j = 0; j < 4; j++) {
        int m = m0 + wm * 64 + mt * 16 + quad * 4 + j;   // C row = quad*4+reg (m89)
        int f = f0 + wn * 64 + nt * 16 + l15;            // C col = lane&15
        float v = acc[mt][nt][j] + bcol[nt];
        if (!is_n) xrz[(size_t)m * 2048 + f] = (bf16_t)v;
        else       xn[(size_t)m * 1024 + (f - 2048)] = v;
      }
    }
  }
}

// ---------------- flag init (ws is 0xAA-poisoned; barrier needs zeros) ----------------
__global__ void k_zero_flags(unsigned* f) {
  for (int i = threadIdx.x; i < NBLK * FLAG_STRIDE; i += 256) f[i] = 0;
}

// Monotone-counter grid barrier, NO cache maintenance at all.
// Release: cross-block data was stored sc1 (write-through), so vmcnt(0) drain
// suffices. Acquire: consumers read hb/rh with sc0+sc1 BYPASS loads, so stale
// L1/L2 lines are unobservable — no buffer_inv. xrz/out keep normal caching.
__device__ inline void gridbar(unsigned* flags, int bid, unsigned p) {
  asm volatile("s_waitcnt vmcnt(0)" ::: "memory");   // per-wave store drain
  __syncthreads();
  if (threadIdx.x == 0)
    __hip_atomic_store(&flags[bid * FLAG_STRIDE], p, __ATOMIC_RELAXED,
                       __HIP_MEMORY_SCOPE_AGENT);
  if (threadIdx.x < NBLK) {
    while (__hip_atomic_load(&flags[threadIdx.x * FLAG_STRIDE], __ATOMIC_RELAXED,
                             __HIP_MEMORY_SCOPE_AGENT) < p)
      __builtin_amdgcn_s_sleep(1);
  }
  __syncthreads();
}

// ---------------- persistent recurrent kernel ----------------
// Block bid owns feature columns [bid*16, bid*16+16) of r, z, n. W_hh rows LDS-resident.
// Wave w handles batches [16w, 16w+16). h lives in 4 regs/thread; hb/rh are the
// bf16 exchange buffers (sc1-written, sc0sc1-read — never through L1/L2).
__global__ __launch_bounds__(256, 1) void k_gru(
    const bf16_t* __restrict__ xrz,  // [65536][2048] bf16 (bias folded)
    const bf16_t* __restrict__ whh,  // [3072][1024] bf16 (r,z,n rows)
    float* __restrict__ out,         // [S*64*1024] holds xn, overwritten with h; +[64*1024] h_n
    bf16_t* __restrict__ hb,
    bf16_t* __restrict__ rh, unsigned* __restrict__ flags)
{
  __shared__ __align__(16) bf16_t wl[48 * 1032];   // 48 rows, +8 bf16 pad (99 KB)
  const int tid  = threadIdx.x;
  const int bid  = blockIdx.x;
  const int lane = tid & 63;
  const int wid  = tid >> 6;
  const int quad = lane >> 4, l15 = lane & 15;

  // stage this block's 48 W_hh rows into LDS
  for (int i = tid; i < 48 * 128; i += 256) {
    int row = i >> 7;            // 0..47 (0-15 r, 16-31 z, 32-47 n)
    int c   = (i & 127) * 8;
    int gr  = (row >> 4) * 1024 + bid * 16 + (row & 15);
    *(bf16x8*)&wl[row * 1032 + c] = *(const bf16x8*)&whh[(size_t)gr * 1024 + c];
  }
  // zero h exchange copy via coherent stores
  for (int i = tid; i < 64 * 4; i += 256) {
    int b = i >> 2, c = i & 3;
    __hip_atomic_store((u64*)(hb + (size_t)b * 1024 + bid * 16) + c, 0ull,
                       __ATOMIC_RELAXED, __HIP_MEMORY_SCOPE_AGENT);
  }
  gridbar(flags, bid, 1);

  const int abase = (wid * 16 + l15) * 1024 + quad * 8;  // A-frag: m=lane&15 (m120)
  const int fg = bid * 16 + l15;                         // this lane's feature column
  unsigned p = 2;

  float hreg[4] = {0.f, 0.f, 0.f, 0.f};     // h[b][fg], thread-private across steps
  float xr_pf[4], xz_pf[4], xn_pf[4];       // operand prefetch regs (cached loads)
#pragma unroll
  for (int j = 0; j < 4; j++) {
    int b = wid * 16 + quad * 4 + j;
    xr_pf[j] = (float)xrz[(size_t)b * 2048 + fg];
    xz_pf[j] = (float)xrz[(size_t)b * 2048 + 1024 + fg];
    xn_pf[j] = out[(size_t)b * 1024 + fg];
  }

  for (int t = 0; t < S_LEN; t++) {
    const int mrow = t * 64;

    // ---- phase A: r,z GEMVs + rh ----
    // Issue all 32 bypass loads of h, then counted waits overlap delivery
    // with MFMA. Phase A has no other VMEM ops (prev gridbar drained vmcnt
    // to 0 with a "memory" clobber), so the counting is exact.
    bf16x8 hbuf[32];
    {
      const bf16_t* hrow = hb + abase;
#pragma unroll
      for (int kk = 0; kk < 32; kk++) hbuf[kk] = ld_coh(hrow + kk * 32);
    }
    f32x4 ar = {}, az = {};
    asm volatile("s_waitcnt vmcnt(16)" ::: "memory");   // oldest 16 loads done
    __builtin_amdgcn_sched_barrier(0);                  // rule #18: pin MFMAs after wait
#pragma unroll
    for (int kk = 0; kk < 16; kk++) {
      bf16x8 br = *(const bf16x8*)&wl[l15 * 1032 + kk * 32 + quad * 8];
      bf16x8 bz = *(const bf16x8*)&wl[(16 + l15) * 1032 + kk * 32 + quad * 8];
      ar = mfma16(hbuf[kk], br, ar);
      az = mfma16(hbuf[kk], bz, az);
    }
    asm volatile("s_waitcnt vmcnt(0)" ::: "memory");
    __builtin_amdgcn_sched_barrier(0);
#pragma unroll
    for (int kk = 16; kk < 32; kk++) {
      bf16x8 br = *(const bf16x8*)&wl[l15 * 1032 + kk * 32 + quad * 8];
      bf16x8 bz = *(const bf16x8*)&wl[(16 + l15) * 1032 + kk * 32 + quad * 8];
      ar = mfma16(hbuf[kk], br, ar);
      az = mfma16(hbuf[kk], bz, az);
    }
    float zreg[4];
#pragma unroll
    for (int j = 0; j < 4; j++) {
      int b = wid * 16 + quad * 4 + j;                   // C row = quad*4+reg
      float rv = fsigmoid(xr_pf[j] + ar[j]);
      float zv = fsigmoid(xz_pf[j] + az[j]);
      zreg[j] = zv;
      st_coh_bf16(&rh[b * 1024 + fg], rv * hreg[j]);     // write-through exchange
    }
    gridbar(flags, bid, p); p++;   // entry vmcnt(0) drains only the 4 rh stores

    // ---- phase B: n GEMV + state update ----
    bf16x8 rbuf[32];
    {
      const bf16_t* rrow = rh + abase;
#pragma unroll
      for (int kk = 0; kk < 32; kk++) rbuf[kk] = ld_coh(rrow + kk * 32);
    }
    f32x4 an = {};
    asm volatile("s_waitcnt vmcnt(16)" ::: "memory");
    __builtin_amdgcn_sched_barrier(0);
#pragma unroll
    for (int kk = 0; kk < 16; kk++) {
      bf16x8 bn = *(const bf16x8*)&wl[(32 + l15) * 1032 + kk * 32 + quad * 8];
      an = mfma16(rbuf[kk], bn, an);
    }
    asm volatile("s_waitcnt vmcnt(0)" ::: "memory");
    __builtin_amdgcn_sched_barrier(0);
    // consume this step's xn before overwriting the prefetch regs
    float xn_cur[4];
#pragma unroll
    for (int j = 0; j < 4; j++) xn_cur[j] = xn_pf[j];
    // prefetch next step's operands (plain cached loads): issued here so their
    // HBM latency hides under the MFMA tail + activations + barrier spin
    if (t + 1 < S_LEN) {
#pragma unroll
      for (int j = 0; j < 4; j++) {
        int b = wid * 16 + quad * 4 + j;
        xr_pf[j] = (float)xrz[(size_t)(mrow + 64 + b) * 2048 + fg];
        xz_pf[j] = (float)xrz[(size_t)(mrow + 64 + b) * 2048 + 1024 + fg];
        xn_pf[j] = out[(size_t)(mrow + 64 + b) * 1024 + fg];
      }
    }
#pragma unroll
    for (int kk = 16; kk < 32; kk++) {
      bf16x8 bn = *(const bf16x8*)&wl[(32 + l15) * 1032 + kk * 32 + quad * 8];
      an = mfma16(rbuf[kk], bn, an);
    }
#pragma unroll
    for (int j = 0; j < 4; j++) {
      int b = wid * 16 + quad * 4 + j;
      size_t oix = (size_t)(mrow + b) * 1024 + fg;
      float nv  = ftanh(xn_cur[j] + an[j]);
      float hv  = (1.f - zreg[j]) * nv + zreg[j] * hreg[j];
      hreg[j] = hv;
      out[oix] = hv;                                     // block-private: plain store
      st_coh_bf16(&hb[b * 1024 + fg], hv);               // write-through exchange
      if (t == S_LEN - 1) out[(size_t)S_LEN * 64 * 1024 + b * 1024 + fg] = hv;
    }
    if (t + 1 < S_LEN) { gridbar(flags, bid, p); p++; }
    // last step: no trailing barrier; kernel-end release flushes final stores
  }
}

extern "C" void kernel_launch(void* const* d_in, const int* in_sizes, int n_in,
                              void* d_out, int out_size, void* d_ws, size_t ws_size,
                              hipStream_t stream) {
  const float* x    = (const float*)d_in[0];
  const float* wihr = (const float*)d_in[1];
  const float* whhr = (const float*)d_in[2];
  const float* wihz = (const float*)d_in[3];
  const float* whhz = (const float*)d_in[4];
  const float* wihn = (const float*)d_in[5];
  const float* whhn = (const float*)d_in[6];
  const float* bihr = (const float*)d_in[7];
  const float* bhhr = (const float*)d_in[8];
  const float* bihz = (const float*)d_in[9];
  const float* bhhz = (const float*)d_in[10];
  const float* bihn = (const float*)d_in[11];
  const float* bhhn = (const float*)d_in[12];
  float* out = (float*)d_out;

  // ws layout (≈396.5 MiB, unchanged footprint; flags in the old hf slot)
  char* w = (char*)d_ws;
  bf16_t*  Xb    = (bf16_t*)(w);                    // 134,217,728 B
  bf16_t*  xrz   = (bf16_t*)(w + 134217728);        // 268,435,456 B
  bf16_t*  wih   = (bf16_t*)(w + 402653184);        //   6,291,456 B
  bf16_t*  whh   = (bf16_t*)(w + 408944640);        //   6,291,456 B
  float*   bias  = (float*) (w + 415236096);        //      12,288 B
  unsigned* flags = (unsigned*)(w + 415248384);     //  16,384 B (padded)
  bf16_t*  hb    = (bf16_t*)(w + 415510528);        //     131,072 B
  bf16_t*  rh    = (bf16_t*)(w + 415641600);        //     131,072 B

  k_cast_x<<<dim3(8388608 / 256), dim3(256), 0, stream>>>(x, Xb, 8388608);
  k_prep_w<<<dim3(1048576 / 256), dim3(256), 0, stream>>>(
      wihr, whhr, wihz, whhz, wihn, whhn,
      bihr, bhhr, bihz, bhhz, bihn, bhhn, wih, whh, bias);
  k_gemm<<<dim3(512, 24), dim3(256), 0, stream>>>(Xb, wih, bias, xrz, out);
  k_zero_flags<<<dim3(1), dim3(256), 0, stream>>>(flags);
  // 64 blocks on 256 CUs: all co-resident on dispatch (plain launch; custom barrier
  // uses monotone counters so a missed value cannot deadlock).
  k_gru<<<dim3(NBLK), dim3(256), 0, stream>>>(xrz, whh, out, hb, rh, flags);
}

// Round 6
// 13368.353 us; speedup vs baseline: 3.2801x; 1.0175x over previous
//
#include <hip/hip_runtime.h>
#include <hip/hip_bf16.h>

typedef __bf16 bf16_t;
typedef __bf16 bf16x8 __attribute__((ext_vector_type(8)));
typedef float  f32x4  __attribute__((ext_vector_type(4)));
typedef unsigned long long u64;

#define S_LEN 1024
#define NBLK  64   // persistent blocks; each owns 16 r + 16 z + 16 n feature rows
#define FLAG_STRIDE 32  // dwords: one flag per 128B to avoid LLC line contention

__device__ inline f32x4 mfma16(bf16x8 a, bf16x8 b, f32x4 c) {
  return __builtin_amdgcn_mfma_f32_16x16x32_bf16(a, b, c, 0, 0, 0);
}
__device__ inline float fsigmoid(float x) {
  x = fmaxf(-30.f, fminf(30.f, x));
  return 1.f / (1.f + __expf(-x));
}
__device__ inline float ftanh(float x) {
  x = fmaxf(-15.f, fminf(15.f, x));
  float e = __expf(2.f * x);
  return (e - 1.f) / (e + 1.f);
}

// Write-through store (sc1): cross-block data never sits dirty in the
// non-coherent per-XCD L2; a plain vmcnt drain makes it globally visible.
__device__ inline void st_coh_bf16(bf16_t* p, float v) {
  bf16_t b = (bf16_t)v;
  __hip_atomic_store((unsigned short*)p, __builtin_bit_cast(unsigned short, b),
                     __ATOMIC_RELAXED, __HIP_MEMORY_SCOPE_AGENT);
}

// Coherence-BYPASSING 16B load (sc0 sc1): misses L1 and L2, reads the
// coherence point directly — stale L1/L2 lines for hb/rh are unobservable,
// so no cache invalidation is ever needed. (Proven in round 3.)
__device__ __forceinline__ bf16x8 ld_coh(const bf16_t* p) {
  f32x4 r;
  asm volatile("global_load_dwordx4 %0, %1, off sc0 sc1" : "=v"(r) : "v"(p));
  return __builtin_bit_cast(bf16x8, r);
}

// ---------------- cast input fp32 -> bf16 ----------------
__global__ void k_cast_x(const float* __restrict__ x, bf16_t* __restrict__ xb, int n8) {
  int i = blockIdx.x * blockDim.x + threadIdx.x;
  if (i >= n8) return;
  const float4* p = (const float4*)(x + (size_t)i * 8);
  float4 a = p[0], b = p[1];
  bf16x8 o;
  o[0]=(bf16_t)a.x; o[1]=(bf16_t)a.y; o[2]=(bf16_t)a.z; o[3]=(bf16_t)a.w;
  o[4]=(bf16_t)b.x; o[5]=(bf16_t)b.y; o[6]=(bf16_t)b.z; o[7]=(bf16_t)b.w;
  *(bf16x8*)(xb + (size_t)i * 8) = o;
}

// ---------------- pack weights (r,z,n concatenated rows), fold biases ----------------
__global__ void k_prep_w(const float* __restrict__ wihr, const float* __restrict__ whhr,
                         const float* __restrict__ wihz, const float* __restrict__ whhz,
                         const float* __restrict__ wihn, const float* __restrict__ whhn,
                         const float* __restrict__ bihr, const float* __restrict__ bhhr,
                         const float* __restrict__ bihz, const float* __restrict__ bhhz,
                         const float* __restrict__ bihn, const float* __restrict__ bhhn,
                         bf16_t* __restrict__ wih, bf16_t* __restrict__ whh,
                         float* __restrict__ bias) {
  int i = blockIdx.x * blockDim.x + threadIdx.x;
  const int M = 1024 * 1024;
  if (i < M) {
    wih[i]       = (bf16_t)wihr[i];
    wih[M + i]   = (bf16_t)wihz[i];
    wih[2*M + i] = (bf16_t)wihn[i];
    whh[i]       = (bf16_t)whhr[i];
    whh[M + i]   = (bf16_t)whhz[i];
    whh[2*M + i] = (bf16_t)whhn[i];
  }
  if (i < 1024) {
    bias[i]        = bihr[i] + bhhr[i];
    bias[1024 + i] = bihz[i] + bhhz[i];
    bias[2048 + i] = bihn[i] + bhhn[i];
  }
}

// ---------------- batched input-projection GEMM ----------------
// C[m][f] = sum_k Xb[m][k] * W[f][k] + bias[f];  M=65536, N=3072, K=1024
// f < 2048 -> bf16 xrz[m][f];  f >= 2048 -> fp32 xn staged into d_out[m][f-2048]
__global__ __launch_bounds__(256) void k_gemm(
    const bf16_t* __restrict__ A, const bf16_t* __restrict__ B,
    const float* __restrict__ bias,
    bf16_t* __restrict__ xrz, float* __restrict__ xn)
{
  __shared__ __align__(16) bf16_t As[128 * 32];
  __shared__ __align__(16) bf16_t Bs[128 * 32];
  const int tid  = threadIdx.x;
  const int lane = tid & 63;
  const int wid  = tid >> 6;
  const int wm   = wid & 1, wn = wid >> 1;
  const int quad = lane >> 4, l15 = lane & 15;
  const int m0 = blockIdx.x * 128;
  const int f0 = blockIdx.y * 128;

  const int r0 = tid >> 2,         o0 = (tid & 3) * 8;
  const int r1 = (tid + 256) >> 2, o1 = ((tid + 256) & 3) * 8;

  const bf16_t* Ag = A + (size_t)m0 * 1024;
  const bf16_t* Bg = B + (size_t)f0 * 1024;

  f32x4 acc[4][4] = {};

  bf16x8 pa0 = *(const bf16x8*)(Ag + r0 * 1024 + o0);
  bf16x8 pa1 = *(const bf16x8*)(Ag + r1 * 1024 + o1);
  bf16x8 pb0 = *(const bf16x8*)(Bg + r0 * 1024 + o0);
  bf16x8 pb1 = *(const bf16x8*)(Bg + r1 * 1024 + o1);

  for (int k0 = 0; k0 < 1024; k0 += 32) {
    __syncthreads();
    *(bf16x8*)&As[r0 * 32 + o0] = pa0;
    *(bf16x8*)&As[r1 * 32 + o1] = pa1;
    *(bf16x8*)&Bs[r0 * 32 + o0] = pb0;
    *(bf16x8*)&Bs[r1 * 32 + o1] = pb1;
    __syncthreads();
    if (k0 + 32 < 1024) {               // prefetch next K-slab under the MFMAs
      const bf16_t* Ag2 = Ag + k0 + 32;
      const bf16_t* Bg2 = Bg + k0 + 32;
      pa0 = *(const bf16x8*)(Ag2 + r0 * 1024 + o0);
      pa1 = *(const bf16x8*)(Ag2 + r1 * 1024 + o1);
      pb0 = *(const bf16x8*)(Bg2 + r0 * 1024 + o0);
      pb1 = *(const bf16x8*)(Bg2 + r1 * 1024 + o1);
    }
    bf16x8 af[4], bfr[4];
#pragma unroll
    for (int t = 0; t < 4; t++) {
      af[t]  = *(const bf16x8*)&As[(wm * 64 + t * 16 + l15) * 32 + quad * 8];
      bfr[t] = *(const bf16x8*)&Bs[(wn * 64 + t * 16 + l15) * 32 + quad * 8];
    }
#pragma unroll
    for (int mt = 0; mt < 4; mt++)
#pragma unroll
      for (int nt = 0; nt < 4; nt++)
        acc[mt][nt] = mfma16(af[mt], bfr[nt], acc[mt][nt]);
  }

  float bcol[4];
#pragma unroll
  for (int nt = 0; nt < 4; nt++) bcol[nt] = bias[f0 + wn * 64 + nt * 16 + l15];

  const bool is_n = (blockIdx.y >= 16);
#pragma unroll
  for (int mt = 0; mt < 4; mt++) {
#pragma unroll
    for (int nt = 0; nt < 4; nt++) {
#pragma unroll
      for (int j = 0; j < 4; j++) {
        int m = m0 + wm * 64 + mt * 16 + quad * 4 + j;   // C row = quad*4+reg (m89)
        int f = f0 + wn * 64 + nt * 16 + l15;            // C col = lane&15
        float v = acc[mt][nt][j] + bcol[nt];
        if (!is_n) xrz[(size_t)m * 2048 + f] = (bf16_t)v;
        else       xn[(size_t)m * 1024 + (f - 2048)] = v;
      }
    }
  }
}

// ---------------- flag init (ws is 0xAA-poisoned; barrier needs zeros) ----------------
__global__ void k_zero_flags(unsigned* f) {
  for (int i = threadIdx.x; i < 4 * NBLK * FLAG_STRIDE; i += 256) f[i] = 0;
}

// ---------------- persistent recurrent kernel ----------------
// Block bid owns feature columns [bid*16,bid*16+16) of r,z,n; W_hh LDS-resident.
// Wave w owns batch rows [16w,16w+16). The exchange is CLOSED per wave-group
// (wave w of every block reads/writes only its own 16 rows), so synchronization
// is 4 independent per-wave barriers: flags[wid][bid], monotone counters,
// no __syncthreads in the loop, no cross-wave skew coupling.
// Release: data stored sc1 (write-through) + per-wave vmcnt(0) drain -> flag.
// Acquire: consumers read hb/rh with sc0sc1 bypass loads -> no cache inval.
__global__ __launch_bounds__(256, 1) void k_gru(
    const bf16_t* __restrict__ xrz,  // [65536][2048] bf16 (bias folded)
    const bf16_t* __restrict__ whh,  // [3072][1024] bf16 (r,z,n rows)
    float* __restrict__ out,         // [S*64*1024] xn staged, overwritten with h; +[64*1024] h_n
    bf16_t* __restrict__ hb,
    bf16_t* __restrict__ rh, unsigned* __restrict__ flags)
{
  __shared__ __align__(16) bf16_t wl[48 * 1032];   // 48 rows, +8 bf16 pad (99 KB)
  const int tid  = threadIdx.x;
  const int bid  = blockIdx.x;
  const int lane = tid & 63;
  const int wid  = tid >> 6;
  const int quad = lane >> 4, l15 = lane & 15;

  // stage this block's 48 W_hh rows into LDS (block-cooperative)
  for (int i = tid; i < 48 * 128; i += 256) {
    int row = i >> 7;            // 0..47 (0-15 r, 16-31 z, 32-47 n)
    int c   = (i & 127) * 8;
    int gr  = (row >> 4) * 1024 + bid * 16 + (row & 15);
    *(bf16x8*)&wl[row * 1032 + c] = *(const bf16x8*)&whh[(size_t)gr * 1024 + c];
  }
  // zero h exchange copy — WAVE-ALIGNED: each wave zeroes exactly its own
  // 16 rows x 16 cols (same footprint as its steady-state publishes), so the
  // per-wave init barrier covers all of this wave-group's consumers.
#pragma unroll
  for (int j = 0; j < 4; j++) {
    int b = wid * 16 + quad * 4 + j;
    st_coh_bf16(&hb[b * 1024 + bid * 16 + l15], 0.f);
  }
  __syncthreads();   // wl ready for all waves (only sync in the kernel)

  unsigned* myflag = flags + (wid * NBLK + bid) * FLAG_STRIDE;
  const unsigned* mypoll = flags + (wid * NBLK + lane) * FLAG_STRIDE;  // lane=block

  // initial per-wave barrier (p=1): own init stores drained, then publish
  asm volatile("s_waitcnt vmcnt(0)" ::: "memory");
  if (lane == 0)
    __hip_atomic_store(myflag, 1u, __ATOMIC_RELAXED, __HIP_MEMORY_SCOPE_AGENT);
  while (!__all(__hip_atomic_load(mypoll, __ATOMIC_RELAXED,
                                  __HIP_MEMORY_SCOPE_AGENT) >= 1u))
    __builtin_amdgcn_s_sleep(1);

  const int abase = (wid * 16 + l15) * 1024 + quad * 8;  // A-frag: m=lane&15 (m120)
  const int fg = bid * 16 + l15;                         // this lane's feature column
  unsigned p = 2;

  float hreg[4] = {0.f, 0.f, 0.f, 0.f};     // h[b][fg], thread-private across steps
  float xr_pf[4], xz_pf[4], xn_pf[4];       // operand prefetch regs (cached loads)
#pragma unroll
  for (int j = 0; j < 4; j++) {
    int b = wid * 16 + quad * 4 + j;
    xr_pf[j] = (float)xrz[(size_t)b * 2048 + fg];
    xz_pf[j] = (float)xrz[(size_t)b * 2048 + 1024 + fg];
    xn_pf[j] = out[(size_t)b * 1024 + fg];
  }

  for (int t = 0; t < S_LEN; t++) {
    const int mrow = t * 64;

    // ---- phase A: r,z GEMVs on h, publish rh ----
    // Poll exit left vmcnt=0, so counted waits over the 32 bypass loads are
    // exact (no other VMEM in flight). Proven consume pattern from round 3.
    bf16x8 hbuf[32];
    {
      const bf16_t* hrow = hb + abase;
#pragma unroll
      for (int kk = 0; kk < 32; kk++) hbuf[kk] = ld_coh(hrow + kk * 32);
    }
    f32x4 ar = {}, az = {};
    asm volatile("s_waitcnt vmcnt(16)" ::: "memory");   // oldest 16 loads done
    __builtin_amdgcn_sched_barrier(0);                  // rule #18: pin MFMAs after wait
#pragma unroll
    for (int kk = 0; kk < 16; kk++) {
      bf16x8 br = *(const bf16x8*)&wl[l15 * 1032 + kk * 32 + quad * 8];
      bf16x8 bz = *(const bf16x8*)&wl[(16 + l15) * 1032 + kk * 32 + quad * 8];
      ar = mfma16(hbuf[kk], br, ar);
      az = mfma16(hbuf[kk], bz, az);
    }
    asm volatile("s_waitcnt vmcnt(0)" ::: "memory");
    __builtin_amdgcn_sched_barrier(0);
#pragma unroll
    for (int kk = 16; kk < 32; kk++) {
      bf16x8 br = *(const bf16x8*)&wl[l15 * 1032 + kk * 32 + quad * 8];
      bf16x8 bz = *(const bf16x8*)&wl[(16 + l15) * 1032 + kk * 32 + quad * 8];
      ar = mfma16(hbuf[kk], br, ar);
      az = mfma16(hbuf[kk], bz, az);
    }
    float zreg[4];
#pragma unroll
    for (int j = 0; j < 4; j++) {
      int b = wid * 16 + quad * 4 + j;                   // C row = quad*4+reg
      float rv = fsigmoid(xr_pf[j] + ar[j]);
      float zv = fsigmoid(xz_pf[j] + az[j]);
      zreg[j] = zv;
      st_coh_bf16(&rh[b * 1024 + fg], rv * hreg[j]);     // write-through exchange
    }
    // per-wave barrier A: drain own 4 rh stores -> flag -> poll
    asm volatile("s_waitcnt vmcnt(0)" ::: "memory");
    if (lane == 0)
      __hip_atomic_store(myflag, p, __ATOMIC_RELAXED, __HIP_MEMORY_SCOPE_AGENT);
    while (!__all(__hip_atomic_load(mypoll, __ATOMIC_RELAXED,
                                    __HIP_MEMORY_SCOPE_AGENT) >= p))
      __builtin_amdgcn_s_sleep(1);
    p++;

    // ---- phase B: n GEMV on rh, state update, publish h ----
    bf16x8 rbuf[32];
    {
      const bf16_t* rrow = rh + abase;
#pragma unroll
      for (int kk = 0; kk < 32; kk++) rbuf[kk] = ld_coh(rrow + kk * 32);
    }
    f32x4 an = {};
    asm volatile("s_waitcnt vmcnt(16)" ::: "memory");
    __builtin_amdgcn_sched_barrier(0);
#pragma unroll
    for (int kk = 0; kk < 16; kk++) {
      bf16x8 bn = *(const bf16x8*)&wl[(32 + l15) * 1032 + kk * 32 + quad * 8];
      an = mfma16(rbuf[kk], bn, an);
    }
    asm volatile("s_waitcnt vmcnt(0)" ::: "memory");
    __builtin_amdgcn_sched_barrier(0);
#pragma unroll
    for (int kk = 16; kk < 32; kk++) {
      bf16x8 bn = *(const bf16x8*)&wl[(32 + l15) * 1032 + kk * 32 + quad * 8];
      an = mfma16(rbuf[kk], bn, an);
    }
#pragma unroll
    for (int j = 0; j < 4; j++) {
      int b = wid * 16 + quad * 4 + j;
      size_t oix = (size_t)(mrow + b) * 1024 + fg;
      float nv  = ftanh(xn_pf[j] + an[j]);
      float hv  = (1.f - zreg[j]) * nv + zreg[j] * hreg[j];
      hreg[j] = hv;
      out[oix] = hv;                                     // thread-private: plain store
      st_coh_bf16(&hb[b * 1024 + fg], hv);               // write-through exchange
      if (t == S_LEN - 1) out[(size_t)S_LEN * 64 * 1024 + b * 1024 + fg] = hv;
    }
    if (t + 1 < S_LEN) {
      // per-wave barrier B: drain -> flag -> PREFETCH (t+1 operands, issued
      // after the flag so their HBM latency hides under the poll, not inside
      // the pre-flag drain) -> poll
      asm volatile("s_waitcnt vmcnt(0)" ::: "memory");
      if (lane == 0)
        __hip_atomic_store(myflag, p, __ATOMIC_RELAXED, __HIP_MEMORY_SCOPE_AGENT);
#pragma unroll
      for (int j = 0; j < 4; j++) {
        int b = wid * 16 + quad * 4 + j;
        xr_pf[j] = (float)xrz[(size_t)(mrow + 64 + b) * 2048 + fg];
        xz_pf[j] = (float)xrz[(size_t)(mrow + 64 + b) * 2048 + 1024 + fg];
        xn_pf[j] = out[(size_t)(mrow + 64 + b) * 1024 + fg];
      }
      while (!__all(__hip_atomic_load(mypoll, __ATOMIC_RELAXED,
                                      __HIP_MEMORY_SCOPE_AGENT) >= p))
        __builtin_amdgcn_s_sleep(1);
      p++;
    }
    // last step: no trailing barrier; kernel-end release flushes final stores
  }
}

extern "C" void kernel_launch(void* const* d_in, const int* in_sizes, int n_in,
                              void* d_out, int out_size, void* d_ws, size_t ws_size,
                              hipStream_t stream) {
  const float* x    = (const float*)d_in[0];
  const float* wihr = (const float*)d_in[1];
  const float* whhr = (const float*)d_in[2];
  const float* wihz = (const float*)d_in[3];
  const float* whhz = (const float*)d_in[4];
  const float* wihn = (const float*)d_in[5];
  const float* whhn = (const float*)d_in[6];
  const float* bihr = (const float*)d_in[7];
  const float* bhhr = (const float*)d_in[8];
  const float* bihz = (const float*)d_in[9];
  const float* bhhz = (const float*)d_in[10];
  const float* bihn = (const float*)d_in[11];
  const float* bhhn = (const float*)d_in[12];
  float* out = (float*)d_out;

  // ws layout (≈396.5 MiB, unchanged footprint; flags now 4 wave-groups x 64)
  char* w = (char*)d_ws;
  bf16_t*  Xb    = (bf16_t*)(w);                    // 134,217,728 B
  bf16_t*  xrz   = (bf16_t*)(w + 134217728);        // 268,435,456 B
  bf16_t*  wih   = (bf16_t*)(w + 402653184);        //   6,291,456 B
  bf16_t*  whh   = (bf16_t*)(w + 408944640);        //   6,291,456 B
  float*   bias  = (float*) (w + 415236096);        //      12,288 B
  unsigned* flags = (unsigned*)(w + 415248384);     //  32,768 B (4x64 padded)
  bf16_t*  hb    = (bf16_t*)(w + 415510528);        //     131,072 B
  bf16_t*  rh    = (bf16_t*)(w + 415641600);        //     131,072 B

  k_cast_x<<<dim3(8388608 / 256), dim3(256), 0, stream>>>(x, Xb, 8388608);
  k_prep_w<<<dim3(1048576 / 256), dim3(256), 0, stream>>>(
      wihr, whhr, wihz, whhz, wihn, whhn,
      bihr, bhhr, bihz, bhhz, bihn, bhhn, wih, whh, bias);
  k_gemm<<<dim3(512, 24), dim3(256), 0, stream>>>(Xb, wih, bias, xrz, out);
  k_zero_flags<<<dim3(1), dim3(256), 0, stream>>>(flags);
  // 64 blocks on 256 CUs: all co-resident; 4 independent per-wave barrier
  // groups (monotone counters, >= test: missed values cannot deadlock).
  k_gru<<<dim3(NBLK), dim3(256), 0, stream>>>(xrz, whh, out, hb, rh, flags);
}